// Round 14
// baseline (370.213 us; speedup 1.0000x reference)
//
#include <hip/hip_runtime.h>
#include <hip/hip_bf16.h>

#define H 128

using bf16x8 = __attribute__((ext_vector_type(8))) short;
using f32x4  = __attribute__((ext_vector_type(4))) float;

__device__ inline unsigned short f2bf(float f) {
    unsigned u = __float_as_uint(f);
    unsigned r = (u + 0x7fffu + ((u >> 16) & 1u)) >> 16;
    return (unsigned short)r;
}
__device__ inline float bf2f(unsigned short b) {
    return __uint_as_float(((unsigned)b) << 16);
}

#define ADD4(d, v) { d.x += v.x; d.y += v.y; d.z += v.z; d.w += v.w; }

// ---------------- CSR build ----------------

__global__ void k_zero_i32(int* __restrict__ p, int n) {
    int i = blockIdx.x * blockDim.x + threadIdx.x;
    if (i < n) p[i] = 0;
}

__global__ void k_count(const int* __restrict__ dst, int* __restrict__ deg, int e) {
    int i = blockIdx.x * blockDim.x + threadIdx.x;
    if (i < e) atomicAdd(&deg[dst[i]], 1);
}

__global__ __launch_bounds__(1024) void k_scan_partial(const int* __restrict__ deg,
                                                       int* __restrict__ partials, int n) {
    __shared__ int sm[1024];
    int t = threadIdx.x;
    int i = blockIdx.x * 1024 + t;
    sm[t] = (i < n) ? deg[i] : 0;
    __syncthreads();
    for (int s = 512; s > 0; s >>= 1) {
        if (t < s) sm[t] += sm[t + s];
        __syncthreads();
    }
    if (t == 0) partials[blockIdx.x] = sm[0];
}

__global__ __launch_bounds__(64) void k_scan_base(int* __restrict__ partials, int nb,
                                                  int* __restrict__ offsets, int n) {
    __shared__ int sm[64];
    int t = threadIdx.x;
    int v = (t < nb) ? partials[t] : 0;
    sm[t] = v;
    __syncthreads();
    for (int off = 1; off < 64; off <<= 1) {
        int x = 0;
        if (t >= off) x = sm[t - off];
        __syncthreads();
        if (t >= off) sm[t] += x;
        __syncthreads();
    }
    if (t < nb) partials[t] = sm[t] - v;
    if (t == 63) offsets[n] = sm[63];
}

__global__ __launch_bounds__(1024) void k_scan_final(const int* __restrict__ deg,
                                                     const int* __restrict__ partials,
                                                     int* __restrict__ offsets,
                                                     int* __restrict__ cursor,
                                                     float* __restrict__ inv_deg, int n) {
    __shared__ int sm[1024];
    int t = threadIdx.x;
    int b = blockIdx.x;
    int i = b * 1024 + t;
    int v = (i < n) ? deg[i] : 0;
    sm[t] = v;
    __syncthreads();
    for (int off = 1; off < 1024; off <<= 1) {
        int x = 0;
        if (t >= off) x = sm[t - off];
        __syncthreads();
        if (t >= off) sm[t] += x;
        __syncthreads();
    }
    if (i < n) {
        int excl = partials[b] + sm[t] - v;
        offsets[i] = excl;
        cursor[i]  = excl;
        inv_deg[i] = 1.0f / fmaxf((float)v, 1.0f);
    }
}

__global__ void k_fill(const int* __restrict__ src, const int* __restrict__ dst,
                       int* __restrict__ cursor, int* __restrict__ csr, int e) {
    int i = blockIdx.x * blockDim.x + threadIdx.x;
    if (i < e) {
        int d = dst[i];
        int pos = atomicAdd(&cursor[d], 1);
        csr[pos] = src[i];
    }
}

// W fragment-major: per layer, fragment fc=(s*8+c): [fc][hl][lane][8] bf16.
// Fragment (s,c): col j = c*16 + (lane&15), k = s*32 + (lane>>4)*8 + jj.
__global__ void k_wsplit(const float* __restrict__ Wl, const float* __restrict__ Wr,
                         unsigned short* __restrict__ Wf, int total) {
    int idx = blockIdx.x * blockDim.x + threadIdx.x;   // (l, s, c, lane)
    if (idx >= total) return;
    int l = idx >> 12;
    int rem = idx & 4095;
    int s = rem >> 9;
    int c = (rem >> 6) & 7;
    int lane = rem & 63;
    int j = c * 16 + (lane & 15);
    int k0 = s * 32 + (lane >> 4) * 8;
    size_t fc = (size_t)(idx >> 6);
    size_t hbase = (fc * 2 * 64 + lane) * 8;
    size_t lbase = hbase + 512;
    for (int jj = 0; jj < 8; ++jj) {
        int k = k0 + jj;
        float v;
        if (k < H) v = Wl[(size_t)l * H * H + j * H + k];
        else       v = Wr[(size_t)l * H * H + j * H + (k - H)];
        unsigned short hi = f2bf(v);
        unsigned short lo = f2bf(v - bf2f(hi));
        Wf[hbase + jj] = hi;
        Wf[lbase + jj] = lo;
    }
}

// ---------------- fused per-layer kernel ----------------
// Block = 256 threads = 4 waves, one 16-row tile per block (grid = n/16).
// Phase 1: 8 groups x 32 lanes; each group aggregates its TWO nodes with an
//          interleaved 4+4-wide joint loop (8 rows in flight -> 2x MLP vs r13),
//          splits to bf16 hi/lo, stores to 8 KB LDS in row-major XOR-swizzled
//          layout (2-way banks on write AND read -> conflict-free).
// Phase 2: wave wv computes col-fragments c = wv*2, wv*2+1:
//          s=0..3 A from LDS; s=4..7 A = h rows direct from global (L2-hot).
// LDS: AL[r<16][hl<2][k<128] ushort, index ^= (r&7)<<3  -> 8 KB.
__global__ __launch_bounds__(256) void k_fused(const float* __restrict__ h,
                                               const int* __restrict__ csr,
                                               const int* __restrict__ offsets,
                                               const float* __restrict__ inv_deg,
                                               const unsigned short* __restrict__ Wf,
                                               const float* __restrict__ bias,
                                               float* __restrict__ out, int n, int relu) {
    __shared__ unsigned short AL[4096];   // 8 KB

    int t = threadIdx.x;

    // ---- Phase 1 ----
    {
        int grp = t >> 5;      // 0..7
        int l4 = t & 31;
        const float4* hv = (const float4*)h;
        int bn0 = grp * 2, bn1 = bn0 + 1;
        int g0 = blockIdx.x * 16 + bn0;
        int g1 = g0 + 1;
        float4 A0 = make_float4(0.f, 0.f, 0.f, 0.f), A1 = A0;
        float4 B0 = A0, B1 = A0;
        int p0 = 0, q0 = 0, p1 = 0, q1 = 0;
        if (g0 < n) { p0 = offsets[g0]; q0 = offsets[g0 + 1]; }
        if (g1 < n) { p1 = offsets[g1]; q1 = offsets[g1 + 1]; }

        // joint loop: 8 rows in flight
        while (p0 + 3 < q0 && p1 + 3 < q1) {
            int iA0 = csr[p0], iA1 = csr[p0 + 1], iA2 = csr[p0 + 2], iA3 = csr[p0 + 3];
            int iB0 = csr[p1], iB1 = csr[p1 + 1], iB2 = csr[p1 + 2], iB3 = csr[p1 + 3];
            float4 vA0 = hv[(size_t)iA0 * 32 + l4];
            float4 vA1 = hv[(size_t)iA1 * 32 + l4];
            float4 vA2 = hv[(size_t)iA2 * 32 + l4];
            float4 vA3 = hv[(size_t)iA3 * 32 + l4];
            float4 vB0 = hv[(size_t)iB0 * 32 + l4];
            float4 vB1 = hv[(size_t)iB1 * 32 + l4];
            float4 vB2 = hv[(size_t)iB2 * 32 + l4];
            float4 vB3 = hv[(size_t)iB3 * 32 + l4];
            ADD4(A0, vA0); ADD4(A1, vA1); ADD4(A0, vA2); ADD4(A1, vA3);
            ADD4(B0, vB0); ADD4(B1, vB1); ADD4(B0, vB2); ADD4(B1, vB3);
            p0 += 4; p1 += 4;
        }
        // node0 remainder
        for (; p0 + 3 < q0; p0 += 4) {
            int i0 = csr[p0], i1 = csr[p0 + 1], i2 = csr[p0 + 2], i3 = csr[p0 + 3];
            float4 v0 = hv[(size_t)i0 * 32 + l4];
            float4 v1 = hv[(size_t)i1 * 32 + l4];
            float4 v2 = hv[(size_t)i2 * 32 + l4];
            float4 v3 = hv[(size_t)i3 * 32 + l4];
            ADD4(A0, v0); ADD4(A1, v1); ADD4(A0, v2); ADD4(A1, v3);
        }
        for (; p0 < q0; ++p0) {
            int i0 = csr[p0];
            float4 v0 = hv[(size_t)i0 * 32 + l4];
            ADD4(A0, v0);
        }
        // node1 remainder
        for (; p1 + 3 < q1; p1 += 4) {
            int i0 = csr[p1], i1 = csr[p1 + 1], i2 = csr[p1 + 2], i3 = csr[p1 + 3];
            float4 v0 = hv[(size_t)i0 * 32 + l4];
            float4 v1 = hv[(size_t)i1 * 32 + l4];
            float4 v2 = hv[(size_t)i2 * 32 + l4];
            float4 v3 = hv[(size_t)i3 * 32 + l4];
            ADD4(B0, v0); ADD4(B1, v1); ADD4(B0, v2); ADD4(B1, v3);
        }
        for (; p1 < q1; ++p1) {
            int i0 = csr[p1];
            float4 v0 = hv[(size_t)i0 * 32 + l4];
            ADD4(B0, v0);
        }

        // write node0
        if (g0 < n) {
            float w = inv_deg[g0];
            float4 acc;
            acc.x = (A0.x + A1.x) * w; acc.y = (A0.y + A1.y) * w;
            acc.z = (A0.z + A1.z) * w; acc.w = (A0.w + A1.w) * w;
            int wb = (bn0 * 256 + l4 * 4) ^ ((bn0 & 7) << 3);
            ushort4 hi4, lo4;
            hi4.x = f2bf(acc.x); lo4.x = f2bf(acc.x - bf2f(hi4.x));
            hi4.y = f2bf(acc.y); lo4.y = f2bf(acc.y - bf2f(hi4.y));
            hi4.z = f2bf(acc.z); lo4.z = f2bf(acc.z - bf2f(hi4.z));
            hi4.w = f2bf(acc.w); lo4.w = f2bf(acc.w - bf2f(hi4.w));
            *(ushort4*)(&AL[wb])       = hi4;
            *(ushort4*)(&AL[wb + 128]) = lo4;
        }
        // write node1
        if (g1 < n) {
            float w = inv_deg[g1];
            float4 acc;
            acc.x = (B0.x + B1.x) * w; acc.y = (B0.y + B1.y) * w;
            acc.z = (B0.z + B1.z) * w; acc.w = (B0.w + B1.w) * w;
            int wb = (bn1 * 256 + l4 * 4) ^ ((bn1 & 7) << 3);
            ushort4 hi4, lo4;
            hi4.x = f2bf(acc.x); lo4.x = f2bf(acc.x - bf2f(hi4.x));
            hi4.y = f2bf(acc.y); lo4.y = f2bf(acc.y - bf2f(hi4.y));
            hi4.z = f2bf(acc.z); lo4.z = f2bf(acc.z - bf2f(hi4.z));
            hi4.w = f2bf(acc.w); lo4.w = f2bf(acc.w - bf2f(hi4.w));
            *(ushort4*)(&AL[wb])       = hi4;
            *(ushort4*)(&AL[wb + 128]) = lo4;
        }
    }
    __syncthreads();

    // ---- Phase 2: GEMM (wave wv owns col-fragments wv*2, wv*2+1) ----
    int wv = t >> 6;
    int lane = t & 63;
    int r16 = lane & 15;
    int kq = lane >> 4;

    f32x4 acc[2];
    acc[0] = (f32x4){0.f, 0.f, 0.f, 0.f};
    acc[1] = (f32x4){0.f, 0.f, 0.f, 0.f};

    // s = 0..3: agg half from swizzled LDS
#pragma unroll
    for (int s = 0; s < 4; ++s) {
        int rb = (r16 * 256 + s * 32 + kq * 8) ^ ((r16 & 7) << 3);
        bf16x8 ah = *(const bf16x8*)(&AL[rb]);
        bf16x8 al = *(const bf16x8*)(&AL[rb + 128]);
#pragma unroll
        for (int j = 0; j < 2; ++j) {
            int c = wv * 2 + j;
            size_t wb = (((size_t)(s * 8 + c) * 2) * 64 + lane) * 8;
            bf16x8 b_hi = *(const bf16x8*)(Wf + wb);
            bf16x8 b_lo = *(const bf16x8*)(Wf + wb + 512);
            acc[j] = __builtin_amdgcn_mfma_f32_16x16x32_bf16(ah, b_hi, acc[j], 0, 0, 0);
            acc[j] = __builtin_amdgcn_mfma_f32_16x16x32_bf16(ah, b_lo, acc[j], 0, 0, 0);
            acc[j] = __builtin_amdgcn_mfma_f32_16x16x32_bf16(al, b_hi, acc[j], 0, 0, 0);
        }
    }

    // s = 4..7: root (h) half, direct global load + in-register split
    int grow = blockIdx.x * 16 + r16;
    bool rok = grow < n;
#pragma unroll
    for (int s = 4; s < 8; ++s) {
        bf16x8 ah = {}, al = {};
        if (rok) {
            const float* hp = h + (size_t)grow * H + (s - 4) * 32 + kq * 8;
            float4 v0 = *(const float4*)hp;
            float4 v1 = *(const float4*)(hp + 4);
            unsigned short x;
            x = f2bf(v0.x); ah[0] = (short)x; al[0] = (short)f2bf(v0.x - bf2f(x));
            x = f2bf(v0.y); ah[1] = (short)x; al[1] = (short)f2bf(v0.y - bf2f(x));
            x = f2bf(v0.z); ah[2] = (short)x; al[2] = (short)f2bf(v0.z - bf2f(x));
            x = f2bf(v0.w); ah[3] = (short)x; al[3] = (short)f2bf(v0.w - bf2f(x));
            x = f2bf(v1.x); ah[4] = (short)x; al[4] = (short)f2bf(v1.x - bf2f(x));
            x = f2bf(v1.y); ah[5] = (short)x; al[5] = (short)f2bf(v1.y - bf2f(x));
            x = f2bf(v1.z); ah[6] = (short)x; al[6] = (short)f2bf(v1.z - bf2f(x));
            x = f2bf(v1.w); ah[7] = (short)x; al[7] = (short)f2bf(v1.w - bf2f(x));
        }
#pragma unroll
        for (int j = 0; j < 2; ++j) {
            int c = wv * 2 + j;
            size_t wb = (((size_t)(s * 8 + c) * 2) * 64 + lane) * 8;
            bf16x8 b_hi = *(const bf16x8*)(Wf + wb);
            bf16x8 b_lo = *(const bf16x8*)(Wf + wb + 512);
            acc[j] = __builtin_amdgcn_mfma_f32_16x16x32_bf16(ah, b_hi, acc[j], 0, 0, 0);
            acc[j] = __builtin_amdgcn_mfma_f32_16x16x32_bf16(ah, b_lo, acc[j], 0, 0, 0);
            acc[j] = __builtin_amdgcn_mfma_f32_16x16x32_bf16(al, b_hi, acc[j], 0, 0, 0);
        }
    }

    // epilogue
#pragma unroll
    for (int j = 0; j < 2; ++j) {
        int col = (wv * 2 + j) * 16 + r16;
        float b = bias[col];
#pragma unroll
        for (int r = 0; r < 4; ++r) {
            int go = blockIdx.x * 16 + kq * 4 + r;
            if (go < n) {
                float v = acc[j][r] + b;
                if (relu) v = fmaxf(v, 0.f);
                out[(size_t)go * H + col] = v;
            }
        }
    }
}

// ---------------- launch ----------------

extern "C" void kernel_launch(void* const* d_in, const int* in_sizes, int n_in,
                              void* d_out, int out_size, void* d_ws, size_t ws_size,
                              hipStream_t stream) {
    const float* x  = (const float*)d_in[0];
    const int*   ei = (const int*)d_in[1];
    const float* Wl = (const float*)d_in[2];
    const float* bl = (const float*)d_in[3];
    const float* Wr = (const float*)d_in[4];
    float* out = (float*)d_out;

    int n = in_sizes[0] / H;
    int e = in_sizes[1] / 2;
    const int* srcp = ei;
    const int* dstp = ei + e;

    char* w = (char*)d_ws;
    auto alloc = [&](size_t bytes) {
        char* p = w;
        w += (bytes + 255) & ~(size_t)255;
        return p;
    };
    int nb = (n + 1023) / 1024;
    int*            csr      = (int*)alloc((size_t)e * 4);
    int*            offsets  = (int*)alloc((size_t)(n + 1) * 4);
    int*            cursor   = (int*)alloc((size_t)n * 4);
    int*            deg      = (int*)alloc((size_t)n * 4);
    float*          inv_deg  = (float*)alloc((size_t)n * 4);
    int*            partials = (int*)alloc(64 * 4);
    unsigned short* Wf       = (unsigned short*)alloc((size_t)3 * 8 * 8 * 2 * 64 * 8 * 2);
    float*          hbuf     = (float*)alloc((size_t)n * H * 4);

    // CSR + inv_deg + W fragment-split (once per launch)
    k_zero_i32<<<(n + 255) / 256, 256, 0, stream>>>(deg, n);
    k_count<<<(e + 255) / 256, 256, 0, stream>>>(dstp, deg, e);
    k_scan_partial<<<nb, 1024, 0, stream>>>(deg, partials, n);
    k_scan_base<<<1, 64, 0, stream>>>(partials, nb, offsets, n);
    k_scan_final<<<nb, 1024, 0, stream>>>(deg, partials, offsets, cursor, inv_deg, n);
    k_fill<<<(e + 255) / 256, 256, 0, stream>>>(srcp, dstp, cursor, csr, e);
    int wtot = 3 * 8 * 8 * 64;
    k_wsplit<<<(wtot + 255) / 256, 256, 0, stream>>>(Wl, Wr, Wf, wtot);

    const float* hin[3]  = {x, out, hbuf};
    float*       hout[3] = {out, hbuf, out};
    int nblk = (n + 15) / 16;
    for (int l = 0; l < 3; ++l) {
        k_fused<<<nblk, 256, 0, stream>>>(hin[l], csr, offsets, inv_deg,
                                          Wf + (size_t)l * 8 * 8 * 2 * 64 * 8,
                                          bl + (size_t)l * H, hout[l], n, l < 2 ? 1 : 0);
    }
}